// Round 9
// baseline (1148.789 us; speedup 1.0000x reference)
//
#include <hip/hip_runtime.h>
#include <math.h>

#define N_NODES 100000
#define N_EDGES 1600000
#define SCAN_NB 256   // blocks in scan kernels
#define SCAN_CH 4     // 256*256*4 = 262144 >= 2N+1

static inline int cdiv(long a, long b) { return (int)((a + b - 1) / b); }

typedef unsigned int uint;
typedef unsigned short ushort;

__device__ inline float bf2f(uint u) { return __uint_as_float(u << 16); }
__device__ inline ushort f2bf(float f) {
    uint u = __float_as_uint(f);
    uint r = ((u >> 16) & 1u) + 0x7fffu;   // RNE
    return (ushort)((u + r) >> 16);
}

// ------------- register-blocked GEMM: C[i,m] = sum_k A[i,k]*B[k,m] ----------
// B row-major KxM. Block = 256 threads; tile = R rows x M cols; each thread
// computes RT rows x 4 cols.
// OUT: 0 = fp32 scalar stores (unaligned base), 1 = fp32 float4 (aligned),
//      2 = bf16 packed, 3 = fp32 scalar to Cv + bf16 packed to Cv2
// ELU: apply elu to outputs before store
// LOSS: fuse sum((C-Xref)^2) per block into partial[blockIdx.x] (needs M==256)
// GUARD: R does not divide nrows -> clamp loads, guard stores
template <int K, int M, int R, int RT, int OUT, bool ELU, bool LOSS, bool GUARD>
__global__ __launch_bounds__(256) void gemm_rb(const float* __restrict__ A,
                                               const float* __restrict__ B,
                                               void* __restrict__ Cv,
                                               void* __restrict__ Cv2,
                                               const float* __restrict__ Xref,
                                               float* __restrict__ partial,
                                               int nrows) {
    constexpr int KC = 32;
    constexpr int TPR = M / 4;        // threads spanning M
    constexpr int G = 256 / TPR;      // row-groups of RT rows
    static_assert(G * RT == R, "tile geometry");
    __shared__ float Blds[KC * M];
    __shared__ float Alds[KC][R];
    const int tcol = threadIdx.x % TPR;
    const int tg   = threadIdx.x / TPR;
    const int rbase = blockIdx.x * R;
    float acc[RT][4] = {};
    for (int k0 = 0; k0 < K; k0 += KC) {
        const float4* Bsrc = reinterpret_cast<const float4*>(B + (size_t)k0 * M);
        float4* Bdst = reinterpret_cast<float4*>(Blds);
#pragma unroll
        for (int i = 0; i < (KC * M / 4) / 256; ++i)
            Bdst[i * 256 + threadIdx.x] = Bsrc[i * 256 + threadIdx.x];
        // A chunk R x KC, stored transposed Alds[k][r]
#pragma unroll
        for (int e = threadIdx.x; e < R * KC; e += 256) {
            int rr = e / KC, kk = e - rr * KC;
            int rg = rbase + rr;
            if (GUARD) rg = min(rg, nrows - 1);
            Alds[kk][rr] = A[(size_t)rg * K + k0 + kk];
        }
        __syncthreads();
#pragma unroll
        for (int kk = 0; kk < KC; ++kk) {
            float ar[RT];
#pragma unroll
            for (int q = 0; q < RT / 4; ++q) {
                float4 av = *reinterpret_cast<const float4*>(&Alds[kk][tg * RT + 4 * q]);
                ar[4 * q] = av.x; ar[4 * q + 1] = av.y;
                ar[4 * q + 2] = av.z; ar[4 * q + 3] = av.w;
            }
            float4 bv = *reinterpret_cast<const float4*>(&Blds[kk * M + tcol * 4]);
            float br[4] = {bv.x, bv.y, bv.z, bv.w};
#pragma unroll
            for (int i = 0; i < RT; ++i)
#pragma unroll
                for (int j = 0; j < 4; ++j)
                    acc[i][j] += ar[i] * br[j];
        }
        __syncthreads();
    }
    float lsum = 0.f;
#pragma unroll
    for (int i = 0; i < RT; ++i) {
        int r = rbase + tg * RT + i;
        if (GUARD && r >= nrows) continue;
        float o0 = acc[i][0], o1 = acc[i][1], o2 = acc[i][2], o3 = acc[i][3];
        if (ELU) {
            o0 = o0 > 0.f ? o0 : expm1f(o0);
            o1 = o1 > 0.f ? o1 : expm1f(o1);
            o2 = o2 > 0.f ? o2 : expm1f(o2);
            o3 = o3 > 0.f ? o3 : expm1f(o3);
        }
        if (OUT == 0 || OUT == 3) {
            float* c = (float*)Cv + (size_t)r * M + tcol * 4;
            c[0] = o0; c[1] = o1; c[2] = o2; c[3] = o3;
        } else if (OUT == 1) {
            float* c = (float*)Cv + (size_t)r * M + tcol * 4;
            *reinterpret_cast<float4*>(c) = make_float4(o0, o1, o2, o3);
        }
        if (OUT == 2 || OUT == 3) {
            void* dst = (OUT == 2) ? Cv : Cv2;
            ushort* c = (ushort*)dst + (size_t)r * M + tcol * 4;
            uint2 w;
            w.x = (uint)f2bf(o0) | ((uint)f2bf(o1) << 16);
            w.y = (uint)f2bf(o2) | ((uint)f2bf(o3) << 16);
            *reinterpret_cast<uint2*>(c) = w;
        }
        if (LOSS) {
            float4 xv = *reinterpret_cast<const float4*>(Xref + (size_t)r * 256 + tcol * 4);
            float d0 = o0 - xv.x, d1 = o1 - xv.y;
            float d2 = o2 - xv.z, d3 = o3 - xv.w;
            lsum += d0 * d0 + d1 * d1 + d2 * d2 + d3 * d3;
        }
    }
    if (LOSS) {
        __shared__ float smRed[4];
#pragma unroll
        for (int off = 32; off > 0; off >>= 1) lsum += __shfl_down(lsum, off);
        int lane = threadIdx.x & 63, w = threadIdx.x >> 6;
        if (lane == 0) smRed[w] = lsum;
        __syncthreads();
        if (threadIdx.x == 0)
            partial[blockIdx.x] = smRed[0] + smRed[1] + smRed[2] + smRed[3];
    }
}

// ---------------- small matrix transpose ------------------------------------
__global__ __launch_bounds__(256) void transpose_kernel(const float* __restrict__ in,
                                                        float* __restrict__ out,
                                                        int rows, int cols) {
    int i = blockIdx.x * 256 + threadIdx.x;
    if (i >= rows * cols) return;
    int r = i / cols, c = i - r * cols;
    out[c * rows + r] = in[i];
}

// ---------------- attention feature dots (bf16 H): all 4 at once ------------
__global__ __launch_bounds__(256) void attn_f4_kernel(const ushort* __restrict__ Hb,
                                                      const float* __restrict__ va,
                                                      const float* __restrict__ vb,
                                                      const float* __restrict__ pva,
                                                      const float* __restrict__ pvb,
                                                      float* __restrict__ f1,
                                                      float* __restrict__ f2,
                                                      float* __restrict__ pf1,
                                                      float* __restrict__ pf2) {
    int wid = (blockIdx.x * 256 + threadIdx.x) >> 6;  // one wave per row
    int lane = threadIdx.x & 63;
    if (wid >= N_NODES) return;
    uint hv = reinterpret_cast<const uint*>(Hb + (size_t)wid * 128)[lane];
    float x0 = bf2f(hv & 0xffffu);
    float x1 = bf2f(hv >> 16);
    int k = 2 * lane;
    float a = x0 * va[k] + x1 * va[k + 1];
    float b = x0 * vb[k] + x1 * vb[k + 1];
    float pa = x0 * pva[k] + x1 * pva[k + 1];
    float pb = x0 * pvb[k] + x1 * pvb[k + 1];
#pragma unroll
    for (int off = 32; off > 0; off >>= 1) {
        a += __shfl_down(a, off);
        b += __shfl_down(b, off);
        pa += __shfl_down(pa, off);
        pb += __shfl_down(pb, off);
    }
    if (lane == 0) { f1[wid] = a; f2[wid] = b; pf1[wid] = pa; pf2[wid] = pb; }
}

// ---------------- unified CSR build (both adjacencies concatenated) ---------
// deg[2N], rp[2N+1], eg[2E], s[2N]; adjacency 2 rows are ids N..2N-1
__global__ __launch_bounds__(256) void hist2_kernel(const int* __restrict__ rows,
                                                    const int* __restrict__ prows,
                                                    int* __restrict__ deg) {
    int e = blockIdx.x * 256 + threadIdx.x;
    if (e >= 2 * N_EDGES) return;
    int r = e < N_EDGES ? rows[e] : N_NODES + prows[e - N_EDGES];
    atomicAdd(&deg[r], 1);
}

#define TOT (2 * N_NODES)
__global__ __launch_bounds__(256) void scan1_kernel(const int* __restrict__ deg,
                                                    int* __restrict__ bsum) {
    __shared__ int sm[256];
    int base = (blockIdx.x * 256 + threadIdx.x) * SCAN_CH;
    int s = 0;
#pragma unroll
    for (int i = 0; i < SCAN_CH; ++i) {
        int idx = base + i;
        if (idx < TOT) s += deg[idx];
    }
    sm[threadIdx.x] = s;
    __syncthreads();
    for (int off = 128; off > 0; off >>= 1) {
        if (threadIdx.x < off) sm[threadIdx.x] += sm[threadIdx.x + off];
        __syncthreads();
    }
    if (threadIdx.x == 0) bsum[blockIdx.x] = sm[0];
}

__global__ void scan2_kernel(int* __restrict__ bsum) {
    if (threadIdx.x != 0) return;
    int run = 0;
    for (int i = 0; i < SCAN_NB; ++i) {
        int t = bsum[i];
        bsum[i] = run;
        run += t;
    }
}

__global__ __launch_bounds__(256) void scan3_kernel(const int* __restrict__ deg,
                                                    const int* __restrict__ bsum,
                                                    int* __restrict__ rp) {
    __shared__ int sm[256];
    int base = (blockIdx.x * 256 + threadIdx.x) * SCAN_CH;
    int s = 0;
#pragma unroll
    for (int i = 0; i < SCAN_CH; ++i) {
        int idx = base + i;
        if (idx < TOT) s += deg[idx];
    }
    sm[threadIdx.x] = s;
    __syncthreads();
    if (threadIdx.x == 0) {
        int run = bsum[blockIdx.x];
        for (int t = 0; t < 256; ++t) { int tmp = sm[t]; sm[t] = run; run += tmp; }
    }
    __syncthreads();
    int off = sm[threadIdx.x];
#pragma unroll
    for (int i = 0; i < SCAN_CH; ++i) {
        int idx = base + i;
        if (idx < TOT) { rp[idx] = off; off += deg[idx]; }
        else if (idx == TOT) rp[idx] = off;
    }
}

// scatter both edge lists into CSR slots (packed {col, exp}) + raw row sums
__global__ __launch_bounds__(256) void scatter2_kernel(const int* __restrict__ rows,
                                                       const int* __restrict__ cols,
                                                       const int* __restrict__ prows,
                                                       const int* __restrict__ pcols,
                                                       const float* __restrict__ f1,
                                                       const float* __restrict__ f2,
                                                       const float* __restrict__ pf1,
                                                       const float* __restrict__ pf2,
                                                       const int* __restrict__ rp,
                                                       int* __restrict__ cur,
                                                       int2* __restrict__ eg,
                                                       float* __restrict__ s) {
    int e = blockIdx.x * 256 + threadIdx.x;
    if (e >= 2 * N_EDGES) return;
    int r, c;
    float fv;
    if (e < N_EDGES) {
        r = rows[e]; c = cols[e];
        fv = f1[r] + f2[c];
    } else {
        int e2 = e - N_EDGES;
        int r0 = prows[e2]; c = pcols[e2];
        fv = pf1[r0] + pf2[c];
        r = N_NODES + r0;
    }
    float v = __expf(fv);
    int pos = rp[r] + atomicAdd(&cur[r], 1);
    eg[pos] = make_int2(c, __float_as_int(v));
    atomicAdd(&s[r], v);
}

// ---------------- fused SpMM on 128-wide bf16 H (encoder) -------------------
// out = elu(0.2*(A1@H)/s1 + 0.8*(A2@H)/s2); one wave per row, 2 dims/lane.
// Masked full-width blocks: no scalar tails, 16 gathers in flight always.
#define SPU 8
__global__ __launch_bounds__(256) void spmm_fused_kernel(const int* __restrict__ rp,
                                                         const int2* __restrict__ eg,
                                                         const float* __restrict__ sarr,
                                                         const ushort* __restrict__ Hb,
                                                         float* __restrict__ out) {
    int r = blockIdx.x * 4 + (threadIdx.x >> 6);
    int lane = threadIdx.x & 63;
    const uint* Hu = reinterpret_cast<const uint*>(Hb);
    float a0 = 0.f, a1 = 0.f, b0 = 0.f, b1 = 0.f;
    int j1 = rp[r], E1 = rp[r + 1];
    int j2 = rp[N_NODES + r], E2 = rp[N_NODES + r + 1];
    int c1 = max(E1 - 1, 0), c2 = max(E2 - 1, 0);
    int nb = max((E1 - j1 + SPU - 1) / SPU, (E2 - j2 + SPU - 1) / SPU);
    for (int b = 0; b < nb; ++b) {
        int2 d1[SPU], d2[SPU];
#pragma unroll
        for (int u = 0; u < SPU; ++u) d1[u] = eg[min(j1 + u, c1)];
#pragma unroll
        for (int u = 0; u < SPU; ++u) d2[u] = eg[min(j2 + u, c2)];
        uint h1[SPU], h2[SPU];
#pragma unroll
        for (int u = 0; u < SPU; ++u) h1[u] = Hu[(size_t)d1[u].x * 64 + lane];
#pragma unroll
        for (int u = 0; u < SPU; ++u) h2[u] = Hu[(size_t)d2[u].x * 64 + lane];
#pragma unroll
        for (int u = 0; u < SPU; ++u) {
            float v1 = (j1 + u < E1) ? __int_as_float(d1[u].y) : 0.f;
            float v2 = (j2 + u < E2) ? __int_as_float(d2[u].y) : 0.f;
            a0 += v1 * bf2f(h1[u] & 0xffffu);
            a1 += v1 * bf2f(h1[u] >> 16);
            b0 += v2 * bf2f(h2[u] & 0xffffu);
            b1 += v2 * bf2f(h2[u] >> 16);
        }
        j1 += SPU; j2 += SPU;
    }
    float s1 = sarr[r], s2 = sarr[N_NODES + r];
    float w1 = s1 > 0.f ? 0.2f / s1 : 0.f;
    float w2 = s2 > 0.f ? 0.8f / s2 : 0.f;
    float o0 = w1 * a0 + w2 * b0;
    float o1 = w1 * a1 + w2 * b1;
    o0 = o0 > 0.f ? o0 : expm1f(o0);
    o1 = o1 > 0.f ? o1 : expm1f(o1);
    *reinterpret_cast<float2*>(out + (size_t)r * 128 + 2 * lane) = make_float2(o0, o1);
}

// ---------------- fused SpMM on 64-wide bf16 Henc (decoder, no elu) ---------
__global__ __launch_bounds__(256) void spmm64_fused_kernel(const int* __restrict__ rp,
                                                           const int2* __restrict__ eg,
                                                           const float* __restrict__ sarr,
                                                           const ushort* __restrict__ Hb,
                                                           float* __restrict__ S) {
    int r = blockIdx.x * 4 + (threadIdx.x >> 6);
    int lane = threadIdx.x & 63;
    float a = 0.f, b = 0.f;
    int j1 = rp[r], E1 = rp[r + 1];
    int j2 = rp[N_NODES + r], E2 = rp[N_NODES + r + 1];
    int c1 = max(E1 - 1, 0), c2 = max(E2 - 1, 0);
    int nb = max((E1 - j1 + SPU - 1) / SPU, (E2 - j2 + SPU - 1) / SPU);
    for (int bb = 0; bb < nb; ++bb) {
        int2 d1[SPU], d2[SPU];
#pragma unroll
        for (int u = 0; u < SPU; ++u) d1[u] = eg[min(j1 + u, c1)];
#pragma unroll
        for (int u = 0; u < SPU; ++u) d2[u] = eg[min(j2 + u, c2)];
        ushort h1[SPU], h2[SPU];
#pragma unroll
        for (int u = 0; u < SPU; ++u) h1[u] = Hb[(size_t)d1[u].x * 64 + lane];
#pragma unroll
        for (int u = 0; u < SPU; ++u) h2[u] = Hb[(size_t)d2[u].x * 64 + lane];
#pragma unroll
        for (int u = 0; u < SPU; ++u) {
            float v1 = (j1 + u < E1) ? __int_as_float(d1[u].y) : 0.f;
            float v2 = (j2 + u < E2) ? __int_as_float(d2[u].y) : 0.f;
            a += v1 * bf2f((uint)h1[u]);
            b += v2 * bf2f((uint)h2[u]);
        }
        j1 += SPU; j2 += SPU;
    }
    float s1 = sarr[r], s2 = sarr[N_NODES + r];
    float w1 = s1 > 0.f ? 0.2f / s1 : 0.f;
    float w2 = s2 > 0.f ? 0.8f / s2 : 0.f;
    S[(size_t)r * 64 + lane] = w1 * a + w2 * b;
}

// ---------------- reductions -----------------------------------------------
__global__ __launch_bounds__(256) void sq_reduce_kernel(const float* __restrict__ a,
                                                        float* __restrict__ acc, int n) {
    __shared__ float sm[4];
    float s = 0.f;
    for (int i = blockIdx.x * 256 + threadIdx.x; i < n; i += gridDim.x * 256) {
        float d = a[i];
        s += d * d;
    }
#pragma unroll
    for (int off = 32; off > 0; off >>= 1) s += __shfl_down(s, off);
    int lane = threadIdx.x & 63, w = threadIdx.x >> 6;
    if (lane == 0) sm[w] = s;
    __syncthreads();
    if (threadIdx.x == 0) atomicAdd(acc, sm[0] + sm[1] + sm[2] + sm[3]);
}

__global__ __launch_bounds__(256) void partial_reduce_kernel(const float* __restrict__ p,
                                                             int n, float* __restrict__ acc) {
    __shared__ float sm[4];
    float s = 0.f;
    for (int i = threadIdx.x; i < n; i += 256) s += p[i];
#pragma unroll
    for (int off = 32; off > 0; off >>= 1) s += __shfl_down(s, off);
    int lane = threadIdx.x & 63, w = threadIdx.x >> 6;
    if (lane == 0) sm[w] = s;
    __syncthreads();
    if (threadIdx.x == 0) atomicAdd(acc, sm[0] + sm[1] + sm[2] + sm[3]);
}

__global__ void finalize_kernel(const float* __restrict__ acc, float* __restrict__ out) {
    out[0] = sqrtf(acc[0]) + 1e-4f * (acc[1] + acc[2]);
}

extern "C" void kernel_launch(void* const* d_in, const int* in_sizes, int n_in,
                              void* d_out, int out_size, void* d_ws, size_t ws_size,
                              hipStream_t stream) {
    const float* X    = (const float*)d_in[0];
    const float* W0   = (const float*)d_in[1];
    const float* W1   = (const float*)d_in[2];
    const float* v00  = (const float*)d_in[3];
    const float* v01  = (const float*)d_in[4];
    const float* pv00 = (const float*)d_in[5];
    const float* pv01 = (const float*)d_in[6];
    const int* rows   = (const int*)d_in[7];
    const int* cols   = (const int*)d_in[8];
    const int* prows  = (const int*)d_in[9];
    const int* pcols  = (const int*)d_in[10];

    float* out  = (float*)d_out;
    float* Henc = out + 1;                                  // N x 64 (misaligned base)
    float* Xrec = out + 1 + (size_t)N_NODES * 64;           // N x 256 (misaligned base)

    // scratch carved out of the dead X_ region [6400001, 32000001):
    //   bufAh  [ 6400004, 12800004)  N x 128 bf16
    //   eg     [12800004, 19200004)  2E int2 (both adjacencies, CSR order)
    //   HencB  [19200004, 22400004)  N x 64 bf16
    //   S      [22400004, 28800004)  N x 64 fp32
    ushort* bufAh  = (ushort*)(out + 6400004);
    int2*   eg     = (int2*)(out + 12800004);
    ushort* HencB  = (ushort*)(out + 19200004);
    float*  S      = out + 22400004;

    float* ws   = (float*)d_ws;
    float* bufB = ws;                                       // N x 128 fp32
    float* f1   = bufB + (size_t)N_NODES * 128;
    float* f2   = f1 + N_NODES;
    float* pf1  = f2 + N_NODES;
    float* pf2  = pf1 + N_NODES;
    int*   deg  = (int*)(pf2 + N_NODES);                    // 2N
    int*   cur  = deg + TOT;                                // 2N
    float* sarr = (float*)(cur + TOT);                      // 2N (raw exp row sums)
    float* acc  = sarr + TOT;                               // 4
    float* W1T  = acc + 4;                                  // 64 x 128
    float* W0T  = W1T + 64 * 128;                           // 128 x 256
    int*   rp   = (int*)(W0T + 128 * 256);                  // 2N+1
    int*   bsum = rp + TOT + 1;                             // SCAN_NB
    float* partial = (float*)(bsum + SCAN_NB);              // n/32 floats

    const int n = N_NODES;
    const int EG2 = cdiv(2 * (long)N_EDGES, 256);

    // 0. weight transposes (tiny)
    transpose_kernel<<<cdiv(128 * 64, 256), 256, 0, stream>>>(W1, W1T, 128, 64);
    transpose_kernel<<<cdiv(256 * 128, 256), 256, 0, stream>>>(W0, W0T, 256, 128);

    // 1. H1 = X @ W0 -> bufAh (bf16)
    gemm_rb<256, 128, 64, 8, 2, false, false, true><<<cdiv(n, 64), 256, 0, stream>>>(
        X, W0, bufAh, nullptr, nullptr, nullptr, n);

    // zero deg(2N) + cur(2N) + s(2N) + acc(4) (contiguous)
    hipMemsetAsync(deg, 0, (3 * (size_t)TOT + 4) * sizeof(int), stream);

    // 2. attention feature dots (one pass over bf16 H1)
    attn_f4_kernel<<<cdiv(n, 4), 256, 0, stream>>>(bufAh, v00, v01, pv00, pv01,
                                                   f1, f2, pf1, pf2);

    // 3. unified CSR build (+ raw exp row sums)
    hist2_kernel<<<EG2, 256, 0, stream>>>(rows, prows, deg);
    scan1_kernel<<<SCAN_NB, 256, 0, stream>>>(deg, bsum);
    scan2_kernel<<<1, 64, 0, stream>>>(bsum);
    scan3_kernel<<<SCAN_NB, 256, 0, stream>>>(deg, bsum, rp);
    scatter2_kernel<<<EG2, 256, 0, stream>>>(rows, cols, prows, pcols,
                                             f1, f2, pf1, pf2, rp, cur, eg, sarr);

    // 4. encoder: bufB = elu(0.2*(A1@H1)/s1 + 0.8*(A2@H1)/s2)
    spmm_fused_kernel<<<n / 4, 256, 0, stream>>>(rp, eg, sarr, bufAh, bufB);

    // 5. Henc = bufB @ W1 -> d_out (fp32) + HencB (bf16 for gather)
    gemm_rb<128, 64, 64, 4, 3, false, false, true><<<cdiv(n, 64), 256, 0, stream>>>(
        bufB, W1, Henc, HencB, nullptr, nullptr, n);

    // 6. decoder spmm on Henc (64-wide): S = 0.2*(A1@Henc)/s1 + 0.8*(A2@Henc)/s2
    spmm64_fused_kernel<<<n / 4, 256, 0, stream>>>(rp, eg, sarr, HencB, S);

    // 7. D = elu(S @ W1T) -> bufB
    gemm_rb<64, 128, 32, 4, 1, true, false, false><<<n / 32, 256, 0, stream>>>(
        S, W1T, bufB, nullptr, nullptr, nullptr, n);

    // 8. X_ = bufB @ W0T -> Xrec, fused loss partials
    gemm_rb<128, 256, 32, 8, 0, false, true, false><<<n / 32, 256, 0, stream>>>(
        bufB, W0T, Xrec, nullptr, X, partial, n);

    // 9. loss
    partial_reduce_kernel<<<1, 256, 0, stream>>>(partial, n / 32, acc + 0);
    sq_reduce_kernel<<<16, 256, 0, stream>>>(W0, acc + 1, 256 * 128);
    sq_reduce_kernel<<<4, 256, 0, stream>>>(W1, acc + 2, 128 * 64);
    finalize_kernel<<<1, 1, 0, stream>>>(acc, out);
}

// Round 10
// 1002.428 us; speedup vs baseline: 1.1460x; 1.1460x over previous
//
#include <hip/hip_runtime.h>
#include <math.h>

#define N_NODES 100000
#define N_EDGES 1600000
#define SCAN_NB 256   // blocks in scan kernels
#define SCAN_CH 4     // 256*256*4 = 262144 >= 2N+1

static inline int cdiv(long a, long b) { return (int)((a + b - 1) / b); }

typedef unsigned int uint;
typedef unsigned short ushort;

__device__ inline float bf2f(uint u) { return __uint_as_float(u << 16); }
__device__ inline ushort f2bf(float f) {
    uint u = __float_as_uint(f);
    uint r = ((u >> 16) & 1u) + 0x7fffu;   // RNE
    return (ushort)((u + r) >> 16);
}

// ------------- register-blocked GEMM: C[i,m] = sum_k A[i,k]*B[k,m] ----------
// B row-major KxM. Block = 256 threads; tile = R rows x M cols; each thread
// computes RT rows x 4 cols.
// OUT: 0 = fp32 scalar stores (unaligned base), 1 = fp32 float4 (aligned),
//      2 = bf16 packed, 3 = fp32 scalar to Cv + bf16 packed to Cv2
// ELU: apply elu to outputs before store
// LOSS: fuse sum((C-Xref)^2) per block into partial[blockIdx.x] (needs M==256)
// GUARD: R does not divide nrows -> clamp loads, guard stores
template <int K, int M, int R, int RT, int OUT, bool ELU, bool LOSS, bool GUARD>
__global__ __launch_bounds__(256) void gemm_rb(const float* __restrict__ A,
                                               const float* __restrict__ B,
                                               void* __restrict__ Cv,
                                               void* __restrict__ Cv2,
                                               const float* __restrict__ Xref,
                                               float* __restrict__ partial,
                                               int nrows) {
    constexpr int KC = 32;
    constexpr int TPR = M / 4;        // threads spanning M
    constexpr int G = 256 / TPR;      // row-groups of RT rows
    static_assert(G * RT == R, "tile geometry");
    __shared__ float Blds[KC * M];
    __shared__ float Alds[KC][R];
    const int tcol = threadIdx.x % TPR;
    const int tg   = threadIdx.x / TPR;
    const int rbase = blockIdx.x * R;
    float acc[RT][4] = {};
    for (int k0 = 0; k0 < K; k0 += KC) {
        const float4* Bsrc = reinterpret_cast<const float4*>(B + (size_t)k0 * M);
        float4* Bdst = reinterpret_cast<float4*>(Blds);
#pragma unroll
        for (int i = 0; i < (KC * M / 4) / 256; ++i)
            Bdst[i * 256 + threadIdx.x] = Bsrc[i * 256 + threadIdx.x];
        // A chunk R x KC, stored transposed Alds[k][r]
#pragma unroll
        for (int e = threadIdx.x; e < R * KC; e += 256) {
            int rr = e / KC, kk = e - rr * KC;
            int rg = rbase + rr;
            if (GUARD) rg = min(rg, nrows - 1);
            Alds[kk][rr] = A[(size_t)rg * K + k0 + kk];
        }
        __syncthreads();
#pragma unroll
        for (int kk = 0; kk < KC; ++kk) {
            float ar[RT];
#pragma unroll
            for (int q = 0; q < RT / 4; ++q) {
                float4 av = *reinterpret_cast<const float4*>(&Alds[kk][tg * RT + 4 * q]);
                ar[4 * q] = av.x; ar[4 * q + 1] = av.y;
                ar[4 * q + 2] = av.z; ar[4 * q + 3] = av.w;
            }
            float4 bv = *reinterpret_cast<const float4*>(&Blds[kk * M + tcol * 4]);
            float br[4] = {bv.x, bv.y, bv.z, bv.w};
#pragma unroll
            for (int i = 0; i < RT; ++i)
#pragma unroll
                for (int j = 0; j < 4; ++j)
                    acc[i][j] += ar[i] * br[j];
        }
        __syncthreads();
    }
    float lsum = 0.f;
#pragma unroll
    for (int i = 0; i < RT; ++i) {
        int r = rbase + tg * RT + i;
        if (GUARD && r >= nrows) continue;
        float o0 = acc[i][0], o1 = acc[i][1], o2 = acc[i][2], o3 = acc[i][3];
        if (ELU) {
            o0 = o0 > 0.f ? o0 : expm1f(o0);
            o1 = o1 > 0.f ? o1 : expm1f(o1);
            o2 = o2 > 0.f ? o2 : expm1f(o2);
            o3 = o3 > 0.f ? o3 : expm1f(o3);
        }
        if (OUT == 0 || OUT == 3) {
            float* c = (float*)Cv + (size_t)r * M + tcol * 4;
            c[0] = o0; c[1] = o1; c[2] = o2; c[3] = o3;
        } else if (OUT == 1) {
            float* c = (float*)Cv + (size_t)r * M + tcol * 4;
            *reinterpret_cast<float4*>(c) = make_float4(o0, o1, o2, o3);
        }
        if (OUT == 2 || OUT == 3) {
            void* dst = (OUT == 2) ? Cv : Cv2;
            ushort* c = (ushort*)dst + (size_t)r * M + tcol * 4;
            uint2 w;
            w.x = (uint)f2bf(o0) | ((uint)f2bf(o1) << 16);
            w.y = (uint)f2bf(o2) | ((uint)f2bf(o3) << 16);
            *reinterpret_cast<uint2*>(c) = w;
        }
        if (LOSS) {
            float4 xv = *reinterpret_cast<const float4*>(Xref + (size_t)r * 256 + tcol * 4);
            float d0 = o0 - xv.x, d1 = o1 - xv.y;
            float d2 = o2 - xv.z, d3 = o3 - xv.w;
            lsum += d0 * d0 + d1 * d1 + d2 * d2 + d3 * d3;
        }
    }
    if (LOSS) {
        __shared__ float smRed[4];
#pragma unroll
        for (int off = 32; off > 0; off >>= 1) lsum += __shfl_down(lsum, off);
        int lane = threadIdx.x & 63, w = threadIdx.x >> 6;
        if (lane == 0) smRed[w] = lsum;
        __syncthreads();
        if (threadIdx.x == 0)
            partial[blockIdx.x] = smRed[0] + smRed[1] + smRed[2] + smRed[3];
    }
}

// ---------------- small matrix transpose ------------------------------------
__global__ __launch_bounds__(256) void transpose_kernel(const float* __restrict__ in,
                                                        float* __restrict__ out,
                                                        int rows, int cols) {
    int i = blockIdx.x * 256 + threadIdx.x;
    if (i >= rows * cols) return;
    int r = i / cols, c = i - r * cols;
    out[c * rows + r] = in[i];
}

// ---------------- attention feature dots (bf16 H): all 4 at once ------------
__global__ __launch_bounds__(256) void attn_f4_kernel(const ushort* __restrict__ Hb,
                                                      const float* __restrict__ va,
                                                      const float* __restrict__ vb,
                                                      const float* __restrict__ pva,
                                                      const float* __restrict__ pvb,
                                                      float* __restrict__ f1,
                                                      float* __restrict__ f2,
                                                      float* __restrict__ pf1,
                                                      float* __restrict__ pf2) {
    int wid = (blockIdx.x * 256 + threadIdx.x) >> 6;  // one wave per row
    int lane = threadIdx.x & 63;
    if (wid >= N_NODES) return;
    uint hv = reinterpret_cast<const uint*>(Hb + (size_t)wid * 128)[lane];
    float x0 = bf2f(hv & 0xffffu);
    float x1 = bf2f(hv >> 16);
    int k = 2 * lane;
    float a = x0 * va[k] + x1 * va[k + 1];
    float b = x0 * vb[k] + x1 * vb[k + 1];
    float pa = x0 * pva[k] + x1 * pva[k + 1];
    float pb = x0 * pvb[k] + x1 * pvb[k + 1];
#pragma unroll
    for (int off = 32; off > 0; off >>= 1) {
        a += __shfl_down(a, off);
        b += __shfl_down(b, off);
        pa += __shfl_down(pa, off);
        pb += __shfl_down(pb, off);
    }
    if (lane == 0) { f1[wid] = a; f2[wid] = b; pf1[wid] = pa; pf2[wid] = pb; }
}

// ---------------- unified CSR build (both adjacencies concatenated) ---------
// deg[2N], rp[2N+1], ccol[2E]; adjacency 2 rows are ids N..2N-1
__global__ __launch_bounds__(256) void hist2_kernel(const int* __restrict__ rows,
                                                    const int* __restrict__ prows,
                                                    int* __restrict__ deg) {
    int e = blockIdx.x * 256 + threadIdx.x;
    if (e >= 2 * N_EDGES) return;
    int r = e < N_EDGES ? rows[e] : N_NODES + prows[e - N_EDGES];
    atomicAdd(&deg[r], 1);
}

#define TOT (2 * N_NODES)
__global__ __launch_bounds__(256) void scan1_kernel(const int* __restrict__ deg,
                                                    int* __restrict__ bsum) {
    __shared__ int sm[256];
    int base = (blockIdx.x * 256 + threadIdx.x) * SCAN_CH;
    int s = 0;
#pragma unroll
    for (int i = 0; i < SCAN_CH; ++i) {
        int idx = base + i;
        if (idx < TOT) s += deg[idx];
    }
    sm[threadIdx.x] = s;
    __syncthreads();
    for (int off = 128; off > 0; off >>= 1) {
        if (threadIdx.x < off) sm[threadIdx.x] += sm[threadIdx.x + off];
        __syncthreads();
    }
    if (threadIdx.x == 0) bsum[blockIdx.x] = sm[0];
}

__global__ void scan2_kernel(int* __restrict__ bsum) {
    if (threadIdx.x != 0) return;
    int run = 0;
    for (int i = 0; i < SCAN_NB; ++i) {
        int t = bsum[i];
        bsum[i] = run;
        run += t;
    }
}

__global__ __launch_bounds__(256) void scan3_kernel(const int* __restrict__ deg,
                                                    const int* __restrict__ bsum,
                                                    int* __restrict__ rp) {
    __shared__ int sm[256];
    int base = (blockIdx.x * 256 + threadIdx.x) * SCAN_CH;
    int s = 0;
#pragma unroll
    for (int i = 0; i < SCAN_CH; ++i) {
        int idx = base + i;
        if (idx < TOT) s += deg[idx];
    }
    sm[threadIdx.x] = s;
    __syncthreads();
    if (threadIdx.x == 0) {
        int run = bsum[blockIdx.x];
        for (int t = 0; t < 256; ++t) { int tmp = sm[t]; sm[t] = run; run += tmp; }
    }
    __syncthreads();
    int off = sm[threadIdx.x];
#pragma unroll
    for (int i = 0; i < SCAN_CH; ++i) {
        int idx = base + i;
        if (idx < TOT) { rp[idx] = off; off += deg[idx]; }
        else if (idx == TOT) rp[idx] = off;
    }
}

// scatter both edge lists into CSR slots: column id only (4B)
__global__ __launch_bounds__(256) void scatter2_kernel(const int* __restrict__ rows,
                                                       const int* __restrict__ cols,
                                                       const int* __restrict__ prows,
                                                       const int* __restrict__ pcols,
                                                       const int* __restrict__ rp,
                                                       int* __restrict__ cur,
                                                       int* __restrict__ ccol) {
    int e = blockIdx.x * 256 + threadIdx.x;
    if (e >= 2 * N_EDGES) return;
    int r, c;
    if (e < N_EDGES) {
        r = rows[e]; c = cols[e];
    } else {
        int e2 = e - N_EDGES;
        r = N_NODES + prows[e2]; c = pcols[e2];
    }
    int pos = rp[r] + atomicAdd(&cur[r], 1);
    ccol[pos] = c;
}

// ---------------- fused SpMM on 128-wide bf16 H (encoder) -------------------
// Attention values recomputed inline: v = exp(f1[r] + f2[c]); softmax row-sum
// accumulated in the same loop. out = elu(0.2*A1H/s1 + 0.8*A2H/s2).
// One wave per row, 2 dims/lane, masked full-width 8-edge blocks.
#define SPU 8
__global__ __launch_bounds__(256) void spmm_fused_kernel(const int* __restrict__ rp,
                                                         const int* __restrict__ ccol,
                                                         const float* __restrict__ f1,
                                                         const float* __restrict__ f2,
                                                         const float* __restrict__ pf1,
                                                         const float* __restrict__ pf2,
                                                         const ushort* __restrict__ Hb,
                                                         float* __restrict__ out) {
    int r = blockIdx.x * 4 + (threadIdx.x >> 6);
    int lane = threadIdx.x & 63;
    const uint* Hu = reinterpret_cast<const uint*>(Hb);
    float a0 = 0.f, a1 = 0.f, b0 = 0.f, b1 = 0.f, sA = 0.f, sB = 0.f;
    float f1r = f1[r], pf1r = pf1[r];
    int j1 = rp[r], E1 = rp[r + 1];
    int j2 = rp[N_NODES + r], E2 = rp[N_NODES + r + 1];
    int c1 = max(E1 - 1, 0), c2 = max(E2 - 1, 0);
    int nb = max((E1 - j1 + SPU - 1) / SPU, (E2 - j2 + SPU - 1) / SPU);
    for (int b = 0; b < nb; ++b) {
        int d1[SPU], d2[SPU];
#pragma unroll
        for (int u = 0; u < SPU; ++u) d1[u] = ccol[min(j1 + u, c1)];
#pragma unroll
        for (int u = 0; u < SPU; ++u) d2[u] = ccol[min(j2 + u, c2)];
        float g1[SPU], g2[SPU];
#pragma unroll
        for (int u = 0; u < SPU; ++u) g1[u] = f2[d1[u]];
#pragma unroll
        for (int u = 0; u < SPU; ++u) g2[u] = pf2[d2[u]];
        uint h1[SPU], h2[SPU];
#pragma unroll
        for (int u = 0; u < SPU; ++u) h1[u] = Hu[(size_t)d1[u] * 64 + lane];
#pragma unroll
        for (int u = 0; u < SPU; ++u) h2[u] = Hu[(size_t)d2[u] * 64 + lane];
#pragma unroll
        for (int u = 0; u < SPU; ++u) {
            float v1 = (j1 + u < E1) ? __expf(f1r + g1[u]) : 0.f;
            float v2 = (j2 + u < E2) ? __expf(pf1r + g2[u]) : 0.f;
            sA += v1; sB += v2;
            a0 += v1 * bf2f(h1[u] & 0xffffu);
            a1 += v1 * bf2f(h1[u] >> 16);
            b0 += v2 * bf2f(h2[u] & 0xffffu);
            b1 += v2 * bf2f(h2[u] >> 16);
        }
        j1 += SPU; j2 += SPU;
    }
    float w1 = sA > 0.f ? 0.2f / sA : 0.f;
    float w2 = sB > 0.f ? 0.8f / sB : 0.f;
    float o0 = w1 * a0 + w2 * b0;
    float o1 = w1 * a1 + w2 * b1;
    o0 = o0 > 0.f ? o0 : expm1f(o0);
    o1 = o1 > 0.f ? o1 : expm1f(o1);
    *reinterpret_cast<float2*>(out + (size_t)r * 128 + 2 * lane) = make_float2(o0, o1);
}

// ---------------- fused SpMM on 64-wide bf16 Henc (decoder, no elu) ---------
__global__ __launch_bounds__(256) void spmm64_fused_kernel(const int* __restrict__ rp,
                                                           const int* __restrict__ ccol,
                                                           const float* __restrict__ f1,
                                                           const float* __restrict__ f2,
                                                           const float* __restrict__ pf1,
                                                           const float* __restrict__ pf2,
                                                           const ushort* __restrict__ Hb,
                                                           float* __restrict__ S) {
    int r = blockIdx.x * 4 + (threadIdx.x >> 6);
    int lane = threadIdx.x & 63;
    float a = 0.f, b = 0.f, sA = 0.f, sB = 0.f;
    float f1r = f1[r], pf1r = pf1[r];
    int j1 = rp[r], E1 = rp[r + 1];
    int j2 = rp[N_NODES + r], E2 = rp[N_NODES + r + 1];
    int c1 = max(E1 - 1, 0), c2 = max(E2 - 1, 0);
    int nb = max((E1 - j1 + SPU - 1) / SPU, (E2 - j2 + SPU - 1) / SPU);
    for (int bb = 0; bb < nb; ++bb) {
        int d1[SPU], d2[SPU];
#pragma unroll
        for (int u = 0; u < SPU; ++u) d1[u] = ccol[min(j1 + u, c1)];
#pragma unroll
        for (int u = 0; u < SPU; ++u) d2[u] = ccol[min(j2 + u, c2)];
        float g1[SPU], g2[SPU];
#pragma unroll
        for (int u = 0; u < SPU; ++u) g1[u] = f2[d1[u]];
#pragma unroll
        for (int u = 0; u < SPU; ++u) g2[u] = pf2[d2[u]];
        ushort h1[SPU], h2[SPU];
#pragma unroll
        for (int u = 0; u < SPU; ++u) h1[u] = Hb[(size_t)d1[u] * 64 + lane];
#pragma unroll
        for (int u = 0; u < SPU; ++u) h2[u] = Hb[(size_t)d2[u] * 64 + lane];
#pragma unroll
        for (int u = 0; u < SPU; ++u) {
            float v1 = (j1 + u < E1) ? __expf(f1r + g1[u]) : 0.f;
            float v2 = (j2 + u < E2) ? __expf(pf1r + g2[u]) : 0.f;
            sA += v1; sB += v2;
            a += v1 * bf2f((uint)h1[u]);
            b += v2 * bf2f((uint)h2[u]);
        }
        j1 += SPU; j2 += SPU;
    }
    float w1 = sA > 0.f ? 0.2f / sA : 0.f;
    float w2 = sB > 0.f ? 0.8f / sB : 0.f;
    S[(size_t)r * 64 + lane] = w1 * a + w2 * b;
}

// ---------------- reductions -----------------------------------------------
__global__ __launch_bounds__(256) void sq_reduce_kernel(const float* __restrict__ a,
                                                        float* __restrict__ acc, int n) {
    __shared__ float sm[4];
    float s = 0.f;
    for (int i = blockIdx.x * 256 + threadIdx.x; i < n; i += gridDim.x * 256) {
        float d = a[i];
        s += d * d;
    }
#pragma unroll
    for (int off = 32; off > 0; off >>= 1) s += __shfl_down(s, off);
    int lane = threadIdx.x & 63, w = threadIdx.x >> 6;
    if (lane == 0) sm[w] = s;
    __syncthreads();
    if (threadIdx.x == 0) atomicAdd(acc, sm[0] + sm[1] + sm[2] + sm[3]);
}

__global__ __launch_bounds__(256) void partial_reduce_kernel(const float* __restrict__ p,
                                                             int n, float* __restrict__ acc) {
    __shared__ float sm[4];
    float s = 0.f;
    for (int i = threadIdx.x; i < n; i += 256) s += p[i];
#pragma unroll
    for (int off = 32; off > 0; off >>= 1) s += __shfl_down(s, off);
    int lane = threadIdx.x & 63, w = threadIdx.x >> 6;
    if (lane == 0) sm[w] = s;
    __syncthreads();
    if (threadIdx.x == 0) atomicAdd(acc, sm[0] + sm[1] + sm[2] + sm[3]);
}

__global__ void finalize_kernel(const float* __restrict__ acc, float* __restrict__ out) {
    out[0] = sqrtf(acc[0]) + 1e-4f * (acc[1] + acc[2]);
}

extern "C" void kernel_launch(void* const* d_in, const int* in_sizes, int n_in,
                              void* d_out, int out_size, void* d_ws, size_t ws_size,
                              hipStream_t stream) {
    const float* X    = (const float*)d_in[0];
    const float* W0   = (const float*)d_in[1];
    const float* W1   = (const float*)d_in[2];
    const float* v00  = (const float*)d_in[3];
    const float* v01  = (const float*)d_in[4];
    const float* pv00 = (const float*)d_in[5];
    const float* pv01 = (const float*)d_in[6];
    const int* rows   = (const int*)d_in[7];
    const int* cols   = (const int*)d_in[8];
    const int* prows  = (const int*)d_in[9];
    const int* pcols  = (const int*)d_in[10];

    float* out  = (float*)d_out;
    float* Henc = out + 1;                                  // N x 64 (misaligned base)
    float* Xrec = out + 1 + (size_t)N_NODES * 64;           // N x 256 (misaligned base)

    // scratch carved out of the dead X_ region [6400001, 32000001):
    //   bufAh  [ 6400004, 12800004)  N x 128 bf16
    //   ccol   [12800004, 16000004)  2E int (CSR column ids)
    //   HencB  [19200004, 22400004)  N x 64 bf16
    //   S      [22400004, 28800004)  N x 64 fp32
    ushort* bufAh  = (ushort*)(out + 6400004);
    int*    ccol   = (int*)(out + 12800004);
    ushort* HencB  = (ushort*)(out + 19200004);
    float*  S      = out + 22400004;

    float* ws   = (float*)d_ws;
    float* bufB = ws;                                       // N x 128 fp32
    float* f1   = bufB + (size_t)N_NODES * 128;
    float* f2   = f1 + N_NODES;
    float* pf1  = f2 + N_NODES;
    float* pf2  = pf1 + N_NODES;
    int*   deg  = (int*)(pf2 + N_NODES);                    // 2N
    int*   cur  = deg + TOT;                                // 2N
    float* acc  = (float*)(cur + TOT);                      // 4
    float* W1T  = acc + 4;                                  // 64 x 128
    float* W0T  = W1T + 64 * 128;                           // 128 x 256
    int*   rp   = (int*)(W0T + 128 * 256);                  // 2N+1
    int*   bsum = rp + TOT + 1;                             // SCAN_NB
    float* partial = (float*)(bsum + SCAN_NB);              // n/32 floats

    const int n = N_NODES;
    const int EG2 = cdiv(2 * (long)N_EDGES, 256);

    // 0. weight transposes (tiny)
    transpose_kernel<<<cdiv(128 * 64, 256), 256, 0, stream>>>(W1, W1T, 128, 64);
    transpose_kernel<<<cdiv(256 * 128, 256), 256, 0, stream>>>(W0, W0T, 256, 128);

    // 1. H1 = X @ W0 -> bufAh (bf16)
    gemm_rb<256, 128, 64, 8, 2, false, false, true><<<cdiv(n, 64), 256, 0, stream>>>(
        X, W0, bufAh, nullptr, nullptr, nullptr, n);

    // zero deg(2N) + cur(2N) + acc(4) (contiguous)
    hipMemsetAsync(deg, 0, (2 * (size_t)TOT + 4) * sizeof(int), stream);

    // 2. attention feature dots (one pass over bf16 H1)
    attn_f4_kernel<<<cdiv(n, 4), 256, 0, stream>>>(bufAh, v00, v01, pv00, pv01,
                                                   f1, f2, pf1, pf2);

    // 3. unified CSR build (column ids only; values recomputed at gather)
    hist2_kernel<<<EG2, 256, 0, stream>>>(rows, prows, deg);
    scan1_kernel<<<SCAN_NB, 256, 0, stream>>>(deg, bsum);
    scan2_kernel<<<1, 64, 0, stream>>>(bsum);
    scan3_kernel<<<SCAN_NB, 256, 0, stream>>>(deg, bsum, rp);
    scatter2_kernel<<<EG2, 256, 0, stream>>>(rows, cols, prows, pcols, rp, cur, ccol);

    // 4. encoder: bufB = elu(0.2*softmax(A1)@H1 + 0.8*softmax(A2)@H1)
    spmm_fused_kernel<<<n / 4, 256, 0, stream>>>(rp, ccol, f1, f2, pf1, pf2, bufAh, bufB);

    // 5. Henc = bufB @ W1 -> d_out (fp32) + HencB (bf16 for gather)
    gemm_rb<128, 64, 64, 4, 3, false, false, true><<<cdiv(n, 64), 256, 0, stream>>>(
        bufB, W1, Henc, HencB, nullptr, nullptr, n);

    // 6. decoder spmm on Henc (64-wide): S = 0.2*sm(A1)@Henc + 0.8*sm(A2)@Henc
    spmm64_fused_kernel<<<n / 4, 256, 0, stream>>>(rp, ccol, f1, f2, pf1, pf2, HencB, S);

    // 7. D = elu(S @ W1T) -> bufB
    gemm_rb<64, 128, 32, 4, 1, true, false, false><<<n / 32, 256, 0, stream>>>(
        S, W1T, bufB, nullptr, nullptr, nullptr, n);

    // 8. X_ = bufB @ W0T -> Xrec, fused loss partials
    gemm_rb<128, 256, 32, 8, 0, false, true, false><<<n / 32, 256, 0, stream>>>(
        bufB, W0T, Xrec, nullptr, X, partial, n);

    // 9. loss
    partial_reduce_kernel<<<1, 256, 0, stream>>>(partial, n / 32, acc + 0);
    sq_reduce_kernel<<<16, 256, 0, stream>>>(W0, acc + 1, 256 * 128);
    sq_reduce_kernel<<<4, 256, 0, stream>>>(W1, acc + 2, 128 * 64);
    finalize_kernel<<<1, 1, 0, stream>>>(acc, out);
}